// Round 1
// baseline (1778.650 us; speedup 1.0000x reference)
//
#include <hip/hip_runtime.h>

// GraphSAGE fused: out = h_self + segsum_r( (h[send] + ef@We + Web) * max(deg_r,1) )
// where [h_self | h] = nf @ W + Wb

constexpr int NN = 50000;   // nodes
constexpr int NE = 800000;  // edges
constexpr int DF = 128;     // node feat
constexpr int DE = 64;      // edge feat
constexpr int EM = 128;     // embed

// ---------------- Kernel 1: node GEMM ----------------
// hW = nf @ W + Wb ; cols [0,128) -> out (h_self), cols [128,256) -> h (ws)
// tile: 64 nodes x 64 cols, block 256 threads (16 egroups x 16 jgroups), 4x4 microtile
__global__ __launch_bounds__(256) void node_gemm(
    const float* __restrict__ nf, const float* __restrict__ W,
    const float* __restrict__ Wb, float* __restrict__ out, float* __restrict__ h)
{
    __shared__ float AT[128][65];   // A tile transposed, +1 pad (conflict-free)
    __shared__ float Bs[128][64];   // W tile
    const int cb = blockIdx.x;      // col block 0..3
    const int rb = blockIdx.y;      // row block
    const int t  = threadIdx.x;
    const int row0 = rb * 64;

    // stage A (64 nodes x 128 k), transposed
    #pragma unroll
    for (int i = 0; i < 32; ++i) {
        int idx = i * 256 + t;          // 0..8191
        int m = idx >> 7, k = idx & 127;
        int node = row0 + m;
        AT[k][m] = (node < NN) ? nf[node * DF + k] : 0.f;
    }
    // stage B (128 k x 64 cols)
    #pragma unroll
    for (int i = 0; i < 32; ++i) {
        int idx = i * 256 + t;
        int k = idx >> 6, j = idx & 63;
        Bs[k][j] = W[k * 256 + cb * 64 + j];
    }
    __syncthreads();

    const int eg = t >> 4, jg = t & 15;
    const int m0 = eg * 4, j0 = jg * 4;
    float acc[4][4] = {};
    for (int k = 0; k < 128; ++k) {
        float a[4];
        #pragma unroll
        for (int i = 0; i < 4; ++i) a[i] = AT[k][m0 + i];
        const float4 bv = *(const float4*)&Bs[k][j0];
        const float b[4] = {bv.x, bv.y, bv.z, bv.w};
        #pragma unroll
        for (int mi = 0; mi < 4; ++mi)
            #pragma unroll
            for (int ji = 0; ji < 4; ++ji)
                acc[mi][ji] += a[mi] * b[ji];
    }

    #pragma unroll
    for (int mi = 0; mi < 4; ++mi) {
        int node = row0 + m0 + mi;
        if (node >= NN) continue;
        #pragma unroll
        for (int ji = 0; ji < 4; ++ji) {
            int c = cb * 64 + j0 + ji;
            float v = acc[mi][ji] + Wb[c];
            if (c < EM) out[node * EM + c] = v;
            else        h[node * EM + (c - EM)] = v;
        }
    }
}

// ---------------- Kernel 2: in-degree histogram ----------------
__global__ void degree_kernel(const int* __restrict__ recv, int* __restrict__ deg)
{
    int i = blockIdx.x * blockDim.x + threadIdx.x;
    if (i < NE) atomicAdd(&deg[recv[i]], 1);
}

// ---------------- Kernel 3: fused edge MLP + gather + scale + scatter ----------------
// tile: 32 edges x 128 cols, block 256 threads (8 egroups x 32 jgroups), 4x4 microtile
// persistent over tiles; We staged in LDS once per block.
__global__ __launch_bounds__(256) void edge_kernel(
    const float* __restrict__ ef, const int* __restrict__ senders,
    const int* __restrict__ receivers, const int* __restrict__ deg,
    const float* __restrict__ We, const float* __restrict__ Web,
    const float* __restrict__ h, float* __restrict__ out, int ntiles)
{
    __shared__ float Ws[64][128];   // We: 64 x 128 (32 KB)
    __shared__ float efT[64][33];   // ef tile transposed, +1 pad
    const int t = threadIdx.x;

    // stage We once
    #pragma unroll
    for (int i = 0; i < 32; ++i) {
        int idx = i * 256 + t;      // 0..8191
        ((float*)Ws)[idx] = We[idx];
    }

    const int eg = t >> 5, jg = t & 31;     // 8 x 32
    const int m0 = eg * 4, j0 = jg * 4;
    float bias[4];
    #pragma unroll
    for (int ji = 0; ji < 4; ++ji) bias[ji] = Web[j0 + ji];

    for (int tile = blockIdx.x; tile < ntiles; tile += gridDim.x) {
        const int e0 = tile * 32;
        __syncthreads();            // protect efT reuse across iterations
        #pragma unroll
        for (int i = 0; i < 8; ++i) {
            int idx = i * 256 + t;  // 0..2047
            int m = idx >> 6, k = idx & 63;
            efT[k][m] = ef[(size_t)(e0 + m) * DE + k];
        }
        __syncthreads();

        float acc[4][4];
        #pragma unroll
        for (int mi = 0; mi < 4; ++mi)
            #pragma unroll
            for (int ji = 0; ji < 4; ++ji) acc[mi][ji] = bias[ji];

        for (int k = 0; k < 64; ++k) {
            float a[4];
            #pragma unroll
            for (int i = 0; i < 4; ++i) a[i] = efT[k][m0 + i];
            const float4 bv = *(const float4*)&Ws[k][j0];
            const float b[4] = {bv.x, bv.y, bv.z, bv.w};
            #pragma unroll
            for (int mi = 0; mi < 4; ++mi)
                #pragma unroll
                for (int ji = 0; ji < 4; ++ji)
                    acc[mi][ji] += a[mi] * b[ji];
        }

        #pragma unroll
        for (int mi = 0; mi < 4; ++mi) {
            const int e = e0 + m0 + mi;
            const int s = senders[e];
            const int r = receivers[e];
            const float d = fmaxf((float)deg[r], 1.0f);
            const float4 hv = *(const float4*)&h[(size_t)s * EM + j0];
            float* op = out + (size_t)r * EM + j0;
            atomicAdd(op + 0, (acc[mi][0] + hv.x) * d);
            atomicAdd(op + 1, (acc[mi][1] + hv.y) * d);
            atomicAdd(op + 2, (acc[mi][2] + hv.z) * d);
            atomicAdd(op + 3, (acc[mi][3] + hv.w) * d);
        }
    }
}

extern "C" void kernel_launch(void* const* d_in, const int* in_sizes, int n_in,
                              void* d_out, int out_size, void* d_ws, size_t ws_size,
                              hipStream_t stream)
{
    (void)in_sizes; (void)n_in; (void)out_size; (void)ws_size;
    const float* nf        = (const float*)d_in[0];
    const int*   senders   = (const int*)d_in[1];
    const int*   receivers = (const int*)d_in[2];
    const float* ef        = (const float*)d_in[3];
    const float* W         = (const float*)d_in[4];
    const float* Wb        = (const float*)d_in[5];
    const float* We        = (const float*)d_in[6];
    const float* Web       = (const float*)d_in[7];
    float* out = (float*)d_out;

    float* h   = (float*)d_ws;                                    // NN*EM floats
    int*   deg = (int*)((char*)d_ws + (size_t)NN * EM * sizeof(float));

    hipMemsetAsync(deg, 0, NN * sizeof(int), stream);

    node_gemm<<<dim3(4, (NN + 63) / 64), 256, 0, stream>>>(nf, W, Wb, out, h);
    degree_kernel<<<(NE + 255) / 256, 256, 0, stream>>>(receivers, deg);
    edge_kernel<<<2048, 256, 0, stream>>>(ef, senders, receivers, deg, We, Web, h, out, NE / 32);
}

// Round 2
// 792.001 us; speedup vs baseline: 2.2458x; 2.2458x over previous
//
#include <hip/hip_runtime.h>

// GraphSAGE, linearity-restructured:
//   out_r = nf_r@W1 + b1 + c_r*( SumNF_r@W2 + SumEF_r@We + deg_r*(b2+be) )
// where c_r = max(deg_r,1), SumNF_r = sum_{e->r} nf[send_e], SumEF_r = sum_{e->r} ef_e.
// No f32 atomics anywhere: CSR build (int atomics) + wave-per-node segment sum.

constexpr int NN = 50000;   // nodes
constexpr int NE = 800000;  // edges
constexpr int DF = 128;     // node feat
constexpr int DE = 64;      // edge feat
constexpr int EM = 128;     // embed

// ---------------- degree histogram (int atomics) ----------------
__global__ void degree_kernel(const int* __restrict__ recv, int* __restrict__ deg)
{
    int i = blockIdx.x * blockDim.x + threadIdx.x;
    if (i < NE) atomicAdd(&deg[recv[i]], 1);
}

// ---------------- exclusive prefix scan over 50000 degrees (1 block) ----------------
__global__ __launch_bounds__(256) void scan_kernel(const int* __restrict__ deg,
                                                   int* __restrict__ start,
                                                   int* __restrict__ cursor)
{
    __shared__ int partial[256];
    __shared__ int offs[256];
    const int t = threadIdx.x;
    const int CH = (NN + 255) / 256;            // 196
    const int lo = t * CH;
    const int hi = min(lo + CH, NN);
    int s = 0;
    for (int i = lo; i < hi; ++i) s += deg[i];
    partial[t] = s;
    __syncthreads();
    if (t == 0) {
        int acc = 0;
        for (int i = 0; i < 256; ++i) { int v = partial[i]; offs[i] = acc; acc += v; }
    }
    __syncthreads();
    int acc = offs[t];
    for (int i = lo; i < hi; ++i) {
        start[i]  = acc;
        cursor[i] = acc;
        acc += deg[i];
    }
    if (hi == NN) start[NN] = acc;              // t==255 writes NE
}

// ---------------- scatter edge ids into CSR slots (int atomics) ----------------
__global__ void scatter_kernel(const int* __restrict__ recv,
                               int* __restrict__ cursor, int* __restrict__ csr_e)
{
    int i = blockIdx.x * blockDim.x + threadIdx.x;
    if (i < NE) {
        int slot = atomicAdd(&cursor[recv[i]], 1);
        csr_e[slot] = i;
    }
}

// ---------------- wave-per-node segment sum of nf[send] and ef[e] ----------------
// writes c_r * SumNF_r (128 f32) and c_r * SumEF_r (64 f32), no atomics.
__global__ __launch_bounds__(256) void aggregate_kernel(
    const int* __restrict__ start, const int* __restrict__ csr_e,
    const int* __restrict__ senders,
    const float* __restrict__ nf, const float* __restrict__ ef,
    float* __restrict__ snf, float* __restrict__ sef)
{
    const int wave = threadIdx.x >> 6;
    const int lane = threadIdx.x & 63;
    const int n = blockIdx.x * 4 + wave;
    if (n >= NN) return;
    const int lo = start[n], hi = start[n + 1];
    float aN0 = 0.f, aN1 = 0.f, aE = 0.f;
    for (int i = lo; i < hi; ++i) {
        const int e = csr_e[i];
        const int s = senders[e];
        const float2 v = *(const float2*)&nf[(size_t)s * DF + lane * 2];
        aN0 += v.x; aN1 += v.y;
        aE  += ef[(size_t)e * DE + lane];
    }
    const float c = fmaxf((float)(hi - lo), 1.0f);
    ((float2*)&snf[(size_t)n * DF])[lane] = make_float2(aN0 * c, aN1 * c);
    sef[(size_t)n * DE + lane] = aE * c;
}

// ---------------- fused final GEMM: out = [nf | snf' | sef'] @ [W1;W2;We] + bias(r) ----
// tile 128 nodes x 128 cols, block 256 (16x16 groups), 8x8 microtile, K=320 in 10x32 chunks
__global__ __launch_bounds__(256) void final_gemm(
    const float* __restrict__ nf, const float* __restrict__ snf, const float* __restrict__ sef,
    const float* __restrict__ W, const float* __restrict__ We,
    const float* __restrict__ Wb, const float* __restrict__ Web,
    const int* __restrict__ deg, float* __restrict__ out)
{
    __shared__ float AT[32][132];   // k x m, stride 132: f4-aligned reads, conflict-free
    __shared__ float Bs[32][128];   // k x j
    const int row0 = blockIdx.x * 128;
    const int t = threadIdx.x;
    const int mg = t >> 4, jg = t & 15;
    const int m0 = mg * 8, j0 = jg * 8;
    float acc[8][8] = {};

    for (int c = 0; c < 10; ++c) {
        __syncthreads();
        // stage A chunk (128 m x 32 k), transposed; sources: nf / snf / sef
        #pragma unroll
        for (int i = 0; i < 16; ++i) {
            int idx = i * 256 + t;
            int m = idx >> 5, kk = idx & 31;
            int node = row0 + m;
            float v = 0.f;
            if (node < NN) {
                if (c < 4)      v = nf [(size_t)node * DF + c * 32 + kk];
                else if (c < 8) v = snf[(size_t)node * DF + (c - 4) * 32 + kk];
                else            v = sef[(size_t)node * DE + (c - 8) * 32 + kk];
            }
            AT[kk][m] = v;
        }
        // stage B chunk (32 k x 128 j); sources: W cols 0:128 / W cols 128:256 / We
        #pragma unroll
        for (int i = 0; i < 16; ++i) {
            int idx = i * 256 + t;
            int kk = idx >> 7, j = idx & 127;
            float v;
            if (c < 4)      v = W [(size_t)(c * 32 + kk) * 256 + j];
            else if (c < 8) v = W [(size_t)((c - 4) * 32 + kk) * 256 + 128 + j];
            else            v = We[(size_t)((c - 8) * 32 + kk) * 128 + j];
            Bs[kk][j] = v;
        }
        __syncthreads();

        for (int kk = 0; kk < 32; ++kk) {
            const float4 a0 = *(const float4*)&AT[kk][m0];
            const float4 a1 = *(const float4*)&AT[kk][m0 + 4];
            const float4 b0 = *(const float4*)&Bs[kk][j0];
            const float4 b1 = *(const float4*)&Bs[kk][j0 + 4];
            const float a[8] = {a0.x, a0.y, a0.z, a0.w, a1.x, a1.y, a1.z, a1.w};
            const float b[8] = {b0.x, b0.y, b0.z, b0.w, b1.x, b1.y, b1.z, b1.w};
            #pragma unroll
            for (int mi = 0; mi < 8; ++mi)
                #pragma unroll
                for (int ji = 0; ji < 8; ++ji)
                    acc[mi][ji] += a[mi] * b[ji];
        }
    }

    #pragma unroll
    for (int mi = 0; mi < 8; ++mi) {
        const int node = row0 + m0 + mi;
        if (node >= NN) continue;
        const float dg = (float)deg[node];
        const float cd = fmaxf(dg, 1.0f) * dg;
        #pragma unroll
        for (int ji = 0; ji < 8; ++ji) {
            const int col = j0 + ji;
            out[(size_t)node * EM + col] = acc[mi][ji] + Wb[col] + cd * (Wb[EM + col] + Web[col]);
        }
    }
}

extern "C" void kernel_launch(void* const* d_in, const int* in_sizes, int n_in,
                              void* d_out, int out_size, void* d_ws, size_t ws_size,
                              hipStream_t stream)
{
    (void)in_sizes; (void)n_in; (void)out_size; (void)ws_size;
    const float* nf        = (const float*)d_in[0];
    const int*   senders   = (const int*)d_in[1];
    const int*   receivers = (const int*)d_in[2];
    const float* ef        = (const float*)d_in[3];
    const float* W         = (const float*)d_in[4];
    const float* Wb        = (const float*)d_in[5];
    const float* We        = (const float*)d_in[6];
    const float* Web       = (const float*)d_in[7];
    float* out = (float*)d_out;

    char* p = (char*)d_ws;
    auto alloc = [&](size_t bytes) { void* q = p; p += (bytes + 255) & ~size_t(255); return q; };
    float* snf    = (float*)alloc((size_t)NN * DF * sizeof(float));   // 25.6 MB
    float* sef    = (float*)alloc((size_t)NN * DE * sizeof(float));   // 12.8 MB
    int*   deg    = (int*)  alloc((size_t)NN * sizeof(int));
    int*   start  = (int*)  alloc((size_t)(NN + 1) * sizeof(int));
    int*   cursor = (int*)  alloc((size_t)NN * sizeof(int));
    int*   csr_e  = (int*)  alloc((size_t)NE * sizeof(int));          // 3.2 MB

    hipMemsetAsync(deg, 0, (size_t)NN * sizeof(int), stream);

    degree_kernel  <<<(NE + 255) / 256, 256, 0, stream>>>(receivers, deg);
    scan_kernel    <<<1, 256, 0, stream>>>(deg, start, cursor);
    scatter_kernel <<<(NE + 255) / 256, 256, 0, stream>>>(receivers, cursor, csr_e);
    aggregate_kernel<<<(NN + 3) / 4, 256, 0, stream>>>(start, csr_e, senders, nf, ef, snf, sef);
    final_gemm     <<<(NN + 127) / 128, 256, 0, stream>>>(nf, snf, sef, W, We, Wb, Web, deg, out);
}

// Round 5
// 551.173 us; speedup vs baseline: 3.2270x; 1.4369x over previous
//
#include <hip/hip_runtime.h>

// GraphSAGE, linearity-restructured:
//   out_r = nf_r@W1 + b1 + c_r*( SumNF_r@W2 + SumEF_r@We + deg_r*(b2+be) )
// c_r = max(deg_r,1). CSR built with rank trick (atomics only in degree pass);
// aggregate is wave-per-node, 4-edge unrolled for memory-level parallelism.

constexpr int NN = 50000;   // nodes
constexpr int NE = 800000;  // edges
constexpr int DF = 128;     // node feat
constexpr int DE = 64;      // edge feat
constexpr int EM = 128;     // embed

// ---------------- degree histogram + per-edge rank ----------------
__global__ void degree_kernel(const int* __restrict__ recv,
                              int* __restrict__ deg, int* __restrict__ rank)
{
    int i = blockIdx.x * blockDim.x + threadIdx.x;
    if (i < NE) rank[i] = atomicAdd(&deg[recv[i]], 1);
}

// ---------------- scan stage 1: per-block partial sums ----------------
__global__ __launch_bounds__(256) void scan1_kernel(const int* __restrict__ deg,
                                                    int* __restrict__ bsum)
{
    __shared__ int sh[256];
    const int t = threadIdx.x;
    const int i = blockIdx.x * 256 + t;
    sh[t] = (i < NN) ? deg[i] : 0;
    __syncthreads();
    for (int off = 128; off > 0; off >>= 1) {
        if (t < off) sh[t] += sh[t + off];
        __syncthreads();
    }
    if (t == 0) bsum[blockIdx.x] = sh[0];
}

// ---------------- scan stage 2: scan the block sums (1 block) ----------------
__global__ __launch_bounds__(256) void scan2_kernel(const int* __restrict__ bsum,
                                                    int* __restrict__ boffs, int nb)
{
    __shared__ int sh[256];
    const int t = threadIdx.x;
    int v = (t < nb) ? bsum[t] : 0;
    int x = v;
    sh[t] = x; __syncthreads();
    for (int off = 1; off < 256; off <<= 1) {
        int y = (t >= off) ? sh[t - off] : 0;
        __syncthreads();
        x += y;
        sh[t] = x;
        __syncthreads();
    }
    if (t < nb) boffs[t] = x - v;   // exclusive
}

// ---------------- scan stage 3: per-block exclusive scan + offset ----------------
__global__ __launch_bounds__(256) void scan3_kernel(const int* __restrict__ deg,
                                                    const int* __restrict__ boffs,
                                                    int* __restrict__ start)
{
    __shared__ int sh[256];
    const int t = threadIdx.x;
    const int i = blockIdx.x * 256 + t;
    const int v = (i < NN) ? deg[i] : 0;
    int x = v;
    sh[t] = x; __syncthreads();
    for (int off = 1; off < 256; off <<= 1) {
        int y = (t >= off) ? sh[t - off] : 0;
        __syncthreads();
        x += y;
        sh[t] = x;
        __syncthreads();
    }
    const int base = boffs[blockIdx.x];
    if (i < NN) start[i] = base + x - v;
    if (i == NN - 1) start[NN] = base + x;
}

// ---------------- scatter (atomic-free): csr[slot] = {edge, sender} ----------------
__global__ void scatter_kernel(const int* __restrict__ recv, const int* __restrict__ rank,
                               const int* __restrict__ senders, const int* __restrict__ start,
                               int2* __restrict__ csr)
{
    int i = blockIdx.x * blockDim.x + threadIdx.x;
    if (i < NE) {
        int slot = start[recv[i]] + rank[i];
        csr[slot] = make_int2(i, senders[i]);
    }
}

// ---------------- wave-per-node segment sum, 4-edge unrolled ----------------
__global__ __launch_bounds__(256) void aggregate_kernel(
    const int* __restrict__ start, const int2* __restrict__ csr,
    const float* __restrict__ nf, const float* __restrict__ ef,
    float* __restrict__ snf, float* __restrict__ sef)
{
    const int wave = threadIdx.x >> 6;
    const int lane = threadIdx.x & 63;
    const int n = blockIdx.x * 4 + wave;
    if (n >= NN) return;
    const int lo = start[n], hi = start[n + 1];
    float aN0 = 0.f, aN1 = 0.f, aE = 0.f;
    int i = lo;
    for (; i + 4 <= hi; i += 4) {
        const int2 c0 = csr[i], c1 = csr[i + 1], c2 = csr[i + 2], c3 = csr[i + 3];
        const float2 v0 = *(const float2*)&nf[(size_t)c0.y * DF + lane * 2];
        const float2 v1 = *(const float2*)&nf[(size_t)c1.y * DF + lane * 2];
        const float2 v2 = *(const float2*)&nf[(size_t)c2.y * DF + lane * 2];
        const float2 v3 = *(const float2*)&nf[(size_t)c3.y * DF + lane * 2];
        const float e0 = ef[(size_t)c0.x * DE + lane];
        const float e1 = ef[(size_t)c1.x * DE + lane];
        const float e2 = ef[(size_t)c2.x * DE + lane];
        const float e3 = ef[(size_t)c3.x * DE + lane];
        aN0 += (v0.x + v1.x) + (v2.x + v3.x);
        aN1 += (v0.y + v1.y) + (v2.y + v3.y);
        aE  += (e0 + e1) + (e2 + e3);
    }
    for (; i < hi; ++i) {
        const int2 c = csr[i];
        const float2 v = *(const float2*)&nf[(size_t)c.y * DF + lane * 2];
        aN0 += v.x; aN1 += v.y;
        aE  += ef[(size_t)c.x * DE + lane];
    }
    const float c = fmaxf((float)(hi - lo), 1.0f);
    ((float2*)&snf[(size_t)n * DF])[lane] = make_float2(aN0 * c, aN1 * c);
    sef[(size_t)n * DE + lane] = aE * c;
}

// ---------------- fused final GEMM: out = [nf | snf' | sef'] @ [W1;W2;We] + bias(r) ----
__global__ __launch_bounds__(256) void final_gemm(
    const float* __restrict__ nf, const float* __restrict__ snf, const float* __restrict__ sef,
    const float* __restrict__ W, const float* __restrict__ We,
    const float* __restrict__ Wb, const float* __restrict__ Web,
    const int* __restrict__ deg, float* __restrict__ out)
{
    __shared__ float AT[32][132];
    __shared__ float Bs[32][128];
    const int row0 = blockIdx.x * 128;
    const int t = threadIdx.x;
    const int mg = t >> 4, jg = t & 15;
    const int m0 = mg * 8, j0 = jg * 8;
    float acc[8][8] = {};

    for (int c = 0; c < 10; ++c) {
        __syncthreads();
        #pragma unroll
        for (int i = 0; i < 16; ++i) {
            int idx = i * 256 + t;
            int m = idx >> 5, kk = idx & 31;
            int node = row0 + m;
            float v = 0.f;
            if (node < NN) {
                if (c < 4)      v = nf [(size_t)node * DF + c * 32 + kk];
                else if (c < 8) v = snf[(size_t)node * DF + (c - 4) * 32 + kk];
                else            v = sef[(size_t)node * DE + (c - 8) * 32 + kk];
            }
            AT[kk][m] = v;
        }
        #pragma unroll
        for (int i = 0; i < 16; ++i) {
            int idx = i * 256 + t;
            int kk = idx >> 7, j = idx & 127;
            float v;
            if (c < 4)      v = W [(size_t)(c * 32 + kk) * 256 + j];
            else if (c < 8) v = W [(size_t)((c - 4) * 32 + kk) * 256 + 128 + j];
            else            v = We[(size_t)((c - 8) * 32 + kk) * 128 + j];
            Bs[kk][j] = v;
        }
        __syncthreads();

        for (int kk = 0; kk < 32; ++kk) {
            const float4 a0 = *(const float4*)&AT[kk][m0];
            const float4 a1 = *(const float4*)&AT[kk][m0 + 4];
            const float4 b0 = *(const float4*)&Bs[kk][j0];
            const float4 b1 = *(const float4*)&Bs[kk][j0 + 4];
            const float a[8] = {a0.x, a0.y, a0.z, a0.w, a1.x, a1.y, a1.z, a1.w};
            const float b[8] = {b0.x, b0.y, b0.z, b0.w, b1.x, b1.y, b1.z, b1.w};
            #pragma unroll
            for (int mi = 0; mi < 8; ++mi)
                #pragma unroll
                for (int ji = 0; ji < 8; ++ji)
                    acc[mi][ji] += a[mi] * b[ji];
        }
    }

    #pragma unroll
    for (int mi = 0; mi < 8; ++mi) {
        const int node = row0 + m0 + mi;
        if (node >= NN) continue;
        const float dg = (float)deg[node];
        const float cd = fmaxf(dg, 1.0f) * dg;
        #pragma unroll
        for (int ji = 0; ji < 8; ++ji) {
            const int col = j0 + ji;
            out[(size_t)node * EM + col] = acc[mi][ji] + Wb[col] + cd * (Wb[EM + col] + Web[col]);
        }
    }
}

extern "C" void kernel_launch(void* const* d_in, const int* in_sizes, int n_in,
                              void* d_out, int out_size, void* d_ws, size_t ws_size,
                              hipStream_t stream)
{
    (void)in_sizes; (void)n_in; (void)out_size; (void)ws_size;
    const float* nf        = (const float*)d_in[0];
    const int*   senders   = (const int*)d_in[1];
    const int*   receivers = (const int*)d_in[2];
    const float* ef        = (const float*)d_in[3];
    const float* W         = (const float*)d_in[4];
    const float* Wb        = (const float*)d_in[5];
    const float* We        = (const float*)d_in[6];
    const float* Web       = (const float*)d_in[7];
    float* out = (float*)d_out;

    char* p = (char*)d_ws;
    auto alloc = [&](size_t bytes) { void* q = p; p += (bytes + 255) & ~size_t(255); return q; };
    float* snf   = (float*)alloc((size_t)NN * DF * sizeof(float));   // 25.6 MB
    float* sef   = (float*)alloc((size_t)NN * DE * sizeof(float));   // 12.8 MB
    int*   deg   = (int*)  alloc((size_t)NN * sizeof(int));
    int*   start = (int*)  alloc((size_t)(NN + 1) * sizeof(int));
    int*   rank  = (int*)  alloc((size_t)NE * sizeof(int));          // 3.2 MB
    int2*  csr   = (int2*) alloc((size_t)NE * sizeof(int2));         // 6.4 MB
    int*   bsum  = (int*)  alloc(256 * sizeof(int));
    int*   boffs = (int*)  alloc(256 * sizeof(int));

    const int NB = (NN + 255) / 256;    // 196

    hipMemsetAsync(deg, 0, (size_t)NN * sizeof(int), stream);

    degree_kernel  <<<(NE + 255) / 256, 256, 0, stream>>>(receivers, deg, rank);
    scan1_kernel   <<<NB, 256, 0, stream>>>(deg, bsum);
    scan2_kernel   <<<1, 256, 0, stream>>>(bsum, boffs, NB);
    scan3_kernel   <<<NB, 256, 0, stream>>>(deg, boffs, start);
    scatter_kernel <<<(NE + 255) / 256, 256, 0, stream>>>(receivers, rank, senders, start, csr);
    aggregate_kernel<<<(NN + 3) / 4, 256, 0, stream>>>(start, csr, nf, ef, snf, sef);
    final_gemm     <<<(NN + 127) / 128, 256, 0, stream>>>(nf, snf, sef, W, We, Wb, Web, deg, out);
}

// Round 8
// 417.088 us; speedup vs baseline: 4.2645x; 1.3215x over previous
//
#include <hip/hip_runtime.h>

// GraphSAGE, linearity-restructured + bf16 MFMA:
//   out_r = nf_r@W1 + b1 + c_r*( SumNF_r@W2 + SumEF_r@We + deg_r*(b2+be) )
// c_r = max(deg_r,1). Aggregate writes RAW sums (bf16); GEMM keeps two
// accumulators (self / neighbor) and applies c_r + degree-bias exactly in
// the f32 epilogue. Weights pre-transposed to bf16 Wt[col][k], k=0..319.

constexpr int NN = 50000;   // nodes
constexpr int NE = 800000;  // edges
constexpr int DF = 128;     // node feat
constexpr int DE = 64;      // edge feat
constexpr int EM = 128;     // embed
constexpr int KT = 320;     // total K = 128+128+64

typedef __attribute__((ext_vector_type(8))) short bf16x8;
typedef __attribute__((ext_vector_type(4))) float f32x4;

__device__ inline unsigned f2bf(float f) {            // RNE f32->bf16 (16-bit result)
    unsigned u = __float_as_uint(f);
    return (u + 0x7FFFu + ((u >> 16) & 1u)) >> 16;
}
__device__ inline float bflo(unsigned u) { return __uint_as_float(u << 16); }
__device__ inline float bfhi(unsigned u) { return __uint_as_float(u & 0xFFFF0000u); }

// ---------------- prep: nf (f32) -> nf16 (bf16) ----------------
__global__ __launch_bounds__(256) void prep_nf16(const float* __restrict__ nf,
                                                 unsigned short* __restrict__ nf16)
{
    int i = blockIdx.x * 256 + threadIdx.x;           // 1.6M threads, 4 floats each
    const float4 v = ((const float4*)nf)[i];
    unsigned lo = f2bf(v.x) | (f2bf(v.y) << 16);
    unsigned hi = f2bf(v.z) | (f2bf(v.w) << 16);
    ((uint2*)nf16)[i] = make_uint2(lo, hi);
}

// ---------------- prep: Wt[col][k] bf16, k in [0,320) ----------------
__global__ void prep_wt(const float* __restrict__ W, const float* __restrict__ We,
                        unsigned short* __restrict__ Wt)
{
    const int k = threadIdx.x;        // 0..319
    const int col = blockIdx.x;       // 0..127
    float v;
    if (k < 128)      v = W[k * 256 + col];                 // W1
    else if (k < 256) v = W[(k - 128) * 256 + 128 + col];   // W2
    else              v = We[(k - 256) * 128 + col];        // We
    Wt[col * KT + k] = (unsigned short)f2bf(v);
}

// ---------------- degree histogram + per-edge rank ----------------
__global__ void degree_kernel(const int* __restrict__ recv,
                              int* __restrict__ deg, int* __restrict__ rank)
{
    int i = blockIdx.x * blockDim.x + threadIdx.x;
    if (i < NE) rank[i] = atomicAdd(&deg[recv[i]], 1);
}

// ---------------- 3-stage exclusive scan ----------------
__global__ __launch_bounds__(256) void scan1_kernel(const int* __restrict__ deg,
                                                    int* __restrict__ bsum)
{
    __shared__ int sh[256];
    const int t = threadIdx.x;
    const int i = blockIdx.x * 256 + t;
    sh[t] = (i < NN) ? deg[i] : 0;
    __syncthreads();
    for (int off = 128; off > 0; off >>= 1) {
        if (t < off) sh[t] += sh[t + off];
        __syncthreads();
    }
    if (t == 0) bsum[blockIdx.x] = sh[0];
}

__global__ __launch_bounds__(256) void scan2_kernel(const int* __restrict__ bsum,
                                                    int* __restrict__ boffs, int nb)
{
    __shared__ int sh[256];
    const int t = threadIdx.x;
    int v = (t < nb) ? bsum[t] : 0;
    int x = v;
    sh[t] = x; __syncthreads();
    for (int off = 1; off < 256; off <<= 1) {
        int y = (t >= off) ? sh[t - off] : 0;
        __syncthreads();
        x += y;
        sh[t] = x;
        __syncthreads();
    }
    if (t < nb) boffs[t] = x - v;
}

__global__ __launch_bounds__(256) void scan3_kernel(const int* __restrict__ deg,
                                                    const int* __restrict__ boffs,
                                                    int* __restrict__ start)
{
    __shared__ int sh[256];
    const int t = threadIdx.x;
    const int i = blockIdx.x * 256 + t;
    const int v = (i < NN) ? deg[i] : 0;
    int x = v;
    sh[t] = x; __syncthreads();
    for (int off = 1; off < 256; off <<= 1) {
        int y = (t >= off) ? sh[t - off] : 0;
        __syncthreads();
        x += y;
        sh[t] = x;
        __syncthreads();
    }
    const int base = boffs[blockIdx.x];
    if (i < NN) start[i] = base + x - v;
    if (i == NN - 1) start[NN] = base + x;
}

// ---------------- scatter (atomic-free): csr[slot] = {edge, sender} ----------------
__global__ void scatter_kernel(const int* __restrict__ recv, const int* __restrict__ rank,
                               const int* __restrict__ senders, const int* __restrict__ start,
                               int2* __restrict__ csr)
{
    int i = blockIdx.x * blockDim.x + threadIdx.x;
    if (i < NE) {
        int slot = start[recv[i]] + rank[i];
        csr[slot] = make_int2(i, senders[i]);
    }
}

// ---------------- wave-per-node RAW segment sums (bf16 out, no scaling) ----------------
__global__ __launch_bounds__(256) void aggregate_kernel(
    const int* __restrict__ start, const int2* __restrict__ csr,
    const unsigned short* __restrict__ nf16, const float* __restrict__ ef,
    unsigned short* __restrict__ snf16, unsigned short* __restrict__ sef16)
{
    const int wave = threadIdx.x >> 6;
    const int lane = threadIdx.x & 63;
    const int n = blockIdx.x * 4 + wave;
    if (n >= NN) return;
    const int lo = start[n], hi = start[n + 1];
    float aN0 = 0.f, aN1 = 0.f, aE = 0.f;
    int i = lo;
    for (; i + 4 <= hi; i += 4) {
        const int2 c0 = csr[i], c1 = csr[i + 1], c2 = csr[i + 2], c3 = csr[i + 3];
        const unsigned u0 = *(const unsigned*)&nf16[(size_t)c0.y * DF + lane * 2];
        const unsigned u1 = *(const unsigned*)&nf16[(size_t)c1.y * DF + lane * 2];
        const unsigned u2 = *(const unsigned*)&nf16[(size_t)c2.y * DF + lane * 2];
        const unsigned u3 = *(const unsigned*)&nf16[(size_t)c3.y * DF + lane * 2];
        const float e0 = ef[(size_t)c0.x * DE + lane];
        const float e1 = ef[(size_t)c1.x * DE + lane];
        const float e2 = ef[(size_t)c2.x * DE + lane];
        const float e3 = ef[(size_t)c3.x * DE + lane];
        aN0 += (bflo(u0) + bflo(u1)) + (bflo(u2) + bflo(u3));
        aN1 += (bfhi(u0) + bfhi(u1)) + (bfhi(u2) + bfhi(u3));
        aE  += (e0 + e1) + (e2 + e3);
    }
    for (; i < hi; ++i) {
        const int2 c = csr[i];
        const unsigned u = *(const unsigned*)&nf16[(size_t)c.y * DF + lane * 2];
        aN0 += bflo(u); aN1 += bfhi(u);
        aE  += ef[(size_t)c.x * DE + lane];
    }
    *(unsigned*)&snf16[(size_t)n * DF + lane * 2] = f2bf(aN0) | (f2bf(aN1) << 16);
    sef16[(size_t)n * DE + lane] = (unsigned short)f2bf(aE);
}

// ---------------- final GEMM (bf16 MFMA 16x16x32) ----------------
// A = [nf16 | snf16 | sef16] (M=50000, K=320), B = Wt^T. Tile 64 rows x 128 cols,
// 4 waves: wave w -> rows (w>>1)*32, cols (w&1)*64. Two acc sets: self (K<128) / nbr.
// LDS: As 64x64 bf16 (8KB) + Bt 128x64 bf16 (16KB), XOR-swizzled (G4).
__device__ inline int swz(int row, int k) {           // byte offset, 16B aligned for k%8==0
    return (row * 128 + k * 2) ^ ((row & 7) << 4);
}

__global__ __launch_bounds__(256) void final_gemm(
    const unsigned short* __restrict__ nf16, const unsigned short* __restrict__ snf16,
    const unsigned short* __restrict__ sef16, const unsigned short* __restrict__ Wt,
    const float* __restrict__ Wb, const float* __restrict__ Web,
    const int* __restrict__ deg, float* __restrict__ out)
{
    __shared__ char smem[8192 + 16384];
    char* As = smem;            // 64 rows x 64 k
    char* Bt = smem + 8192;     // 128 cols x 64 k
    const int t = threadIdx.x;
    const int l = t & 63;
    const int w = t >> 6;
    const int wr = (w >> 1) * 32;   // wave row offset
    const int wc = (w & 1) * 64;    // wave col offset
    const int row0 = blockIdx.x * 64;

    f32x4 accS[2][4] = {};
    f32x4 accN[2][4] = {};

    for (int c = 0; c < 5; ++c) {
        if (c) __syncthreads();
        // stage A chunk: 64 rows x 64 k (bf16)
        const unsigned short* srcA = (c < 2) ? nf16 + c * 64
                                   : (c < 4) ? snf16 + (c - 2) * 64
                                             : sef16;
        const int strideA = (c < 4) ? DF : DE;
        #pragma unroll
        for (int p = 0; p < 2; ++p) {
            const int row = (t >> 3) + p * 32;
            const int kb = (t & 7) * 8;
            const int node = row0 + row;
            uint4 v = make_uint4(0, 0, 0, 0);
            if (node < NN) v = *(const uint4*)&srcA[(size_t)node * strideA + kb];
            *(uint4*)(As + swz(row, kb)) = v;
        }
        // stage B chunk: 128 cols x 64 k (bf16) from Wt[col][c*64 + k]
        #pragma unroll
        for (int p = 0; p < 4; ++p) {
            const int col = (t >> 3) + p * 32;
            const int kb = (t & 7) * 8;
            *(uint4*)(Bt + swz(col, kb)) = *(const uint4*)&Wt[(size_t)col * KT + c * 64 + kb];
        }
        __syncthreads();

        #pragma unroll
        for (int ks = 0; ks < 2; ++ks) {
            bf16x8 a[2], b[4];
            const int kf = ks * 32 + (l >> 4) * 8;
            #pragma unroll
            for (int r = 0; r < 2; ++r)
                a[r] = *(const bf16x8*)(As + swz(wr + r * 16 + (l & 15), kf));
            #pragma unroll
            for (int cc = 0; cc < 4; ++cc)
                b[cc] = *(const bf16x8*)(Bt + swz(wc + cc * 16 + (l & 15), kf));
            if (c < 2) {
                #pragma unroll
                for (int r = 0; r < 2; ++r)
                    #pragma unroll
                    for (int cc = 0; cc < 4; ++cc)
                        accS[r][cc] = __builtin_amdgcn_mfma_f32_16x16x32_bf16(
                            a[r], b[cc], accS[r][cc], 0, 0, 0);
            } else {
                #pragma unroll
                for (int r = 0; r < 2; ++r)
                    #pragma unroll
                    for (int cc = 0; cc < 4; ++cc)
                        accN[r][cc] = __builtin_amdgcn_mfma_f32_16x16x32_bf16(
                            a[r], b[cc], accN[r][cc], 0, 0, 0);
            }
        }
    }

    // epilogue: out = accS + b1 + cmax*(accN + dg*bc),  bc = b2 + be
    #pragma unroll
    for (int r = 0; r < 2; ++r) {
        #pragma unroll
        for (int j = 0; j < 4; ++j) {
            const int node = row0 + wr + r * 16 + (l >> 4) * 4 + j;
            if (node >= NN) continue;
            const float dg = (float)deg[node];
            const float cm = fmaxf(dg, 1.0f);
            #pragma unroll
            for (int cc = 0; cc < 4; ++cc) {
                const int col = wc + cc * 16 + (l & 15);
                const float b1 = Wb[col];
                const float bc = Wb[EM + col] + Web[col];
                out[(size_t)node * EM + col] =
                    accS[r][cc][j] + b1 + cm * (accN[r][cc][j] + dg * bc);
            }
        }
    }
}

extern "C" void kernel_launch(void* const* d_in, const int* in_sizes, int n_in,
                              void* d_out, int out_size, void* d_ws, size_t ws_size,
                              hipStream_t stream)
{
    (void)in_sizes; (void)n_in; (void)out_size; (void)ws_size;
    const float* nf        = (const float*)d_in[0];
    const int*   senders   = (const int*)d_in[1];
    const int*   receivers = (const int*)d_in[2];
    const float* ef        = (const float*)d_in[3];
    const float* W         = (const float*)d_in[4];
    const float* Wb        = (const float*)d_in[5];
    const float* We        = (const float*)d_in[6];
    const float* Web       = (const float*)d_in[7];
    float* out = (float*)d_out;

    char* p = (char*)d_ws;
    auto alloc = [&](size_t bytes) { void* q = p; p += (bytes + 255) & ~size_t(255); return q; };
    unsigned short* nf16  = (unsigned short*)alloc((size_t)NN * DF * 2);  // 12.8 MB
    unsigned short* snf16 = (unsigned short*)alloc((size_t)NN * DF * 2);  // 12.8 MB
    unsigned short* sef16 = (unsigned short*)alloc((size_t)NN * DE * 2);  //  6.4 MB
    unsigned short* Wt    = (unsigned short*)alloc((size_t)EM * KT * 2);  //  80 KB
    int*   deg   = (int*)  alloc((size_t)NN * sizeof(int));
    int*   start = (int*)  alloc((size_t)(NN + 1) * sizeof(int));
    int*   rank  = (int*)  alloc((size_t)NE * sizeof(int));               //  3.2 MB
    int2*  csr   = (int2*) alloc((size_t)NE * sizeof(int2));              //  6.4 MB
    int*   bsum  = (int*)  alloc(256 * sizeof(int));
    int*   boffs = (int*)  alloc(256 * sizeof(int));

    const int NB = (NN + 255) / 256;    // 196

    hipMemsetAsync(deg, 0, (size_t)NN * sizeof(int), stream);

    prep_nf16     <<<(NN * DF / 4 + 255) / 256, 256, 0, stream>>>(nf, nf16);
    prep_wt       <<<EM, KT, 0, stream>>>(W, We, Wt);
    degree_kernel <<<(NE + 255) / 256, 256, 0, stream>>>(receivers, deg, rank);
    scan1_kernel  <<<NB, 256, 0, stream>>>(deg, bsum);
    scan2_kernel  <<<1, 256, 0, stream>>>(bsum, boffs, NB);
    scan3_kernel  <<<NB, 256, 0, stream>>>(deg, boffs, start);
    scatter_kernel<<<(NE + 255) / 256, 256, 0, stream>>>(receivers, rank, senders, start, csr);
    aggregate_kernel<<<(NN + 3) / 4, 256, 0, stream>>>(start, csr, nf16, ef, snf16, sef16);
    final_gemm    <<<(NN + 63) / 64, 256, 0, stream>>>(nf16, snf16, sef16, Wt, Wb, Web, deg, out);
}